// Round 2
// baseline (1121.100 us; speedup 1.0000x reference)
//
#include <hip/hip_runtime.h>
#include <hip/hip_cooperative_groups.h>

namespace cg = cooperative_groups;

#define NN   2048
#define ROWS 4096          // B*N
#define RPB  16            // rows per block
#define CSPLIT 4           // column splits; block covers 256 float4 cols
#define NBY  (ROWS/RPB)    // 256
#define NCSL 8             // c-accumulator slices
#define PSTR 257           // LDS partial stride

__device__ __forceinline__ float fsig(float x) {
    float e = __expf(-x);
    return __builtin_amdgcn_rcpf(1.0f + e);
}

// ---------------------------------------------------------------------------
// Fused-path pass body.  CB slices are host-pre-zeroed (no czero here).
// stCur/stPrev/stPP: rotating LDS aS state (aS_T / aS_{T-1} / aS_{T-2}).
// d0/d1: register-resident F1-F0 (constant across passes, filled at T==0).
// ---------------------------------------------------------------------------
template<int T>
__device__ __forceinline__ void do_pass(
    float* __restrict__ stCur, const float* __restrict__ stPrev,
    const float* __restrict__ stPP,
    float* __restrict__ sdif, float* __restrict__ cdif,
    float* __restrict__ part,
    float (&d0)[RPB], float (&d1)[RPB],
    const float4* __restrict__ F,
    const float2* __restrict__ S2, const float2* __restrict__ C2,
    const float* __restrict__ rprev, const float* __restrict__ cprev,
    float* __restrict__ rout, float* __restrict__ cout,
    float* __restrict__ aSout, float4* __restrict__ outF,
    int tid, int sx, int by, int bloc, int row0, int base,
    float w0, float w1)
{
    // ---- prologue: state for the 528 indices this block touches ----
    for (int idx = tid; idx < 528; idx += 256) {
        int il = (idx < 512) ? (sx * 512 + idx) : (bloc * RPB + idx - 512);
        int g  = base + il;
        float cur;
        if (T == 0) {
            float2 sv = S2[g], cv = C2[g];
            float sd = sv.y - sv.x;
            sdif[idx] = sd;
            cdif[idx] = cv.x - cv.y;
            cur = fsig(sd);                       // aS_0
        } else {
            float rs = rprev[0*ROWS+g] + rprev[1*ROWS+g]
                     + rprev[2*ROWS+g] + rprev[3*ROWS+g];
            float cs = 0.0f;
#pragma unroll
            for (int s = 0; s < NCSL; s++) cs += cprev[s*ROWS + g];
            float qc = (T == 1) ? fsig(cdif[idx])                      // qC0_0
                                : fsig(cdif[idx] - w0 * stPP[idx]);    // qC0_{T-1}
            cur = fsig(sdif[idx] + w1*cs - w0*qc - w1*rs);             // aS_T
        }
        stCur[idx] = cur;
        if (T >= 3 && sx == 0 && idx >= 512) aSout[g] = cur;  // aS_3/aS_4 for kfin
    }
    __syncthreads();

    const int j = sx * 256 + tid;                  // float4 column
    const float wq0 = 1.0f - stCur[2*tid];
    const float wq1 = 1.0f - stCur[2*tid + 1];
    const float bp0 = (T == 0) ? 0.0f : 1.0f - stPrev[2*tid];
    const float bp1 = (T == 0) ? 0.0f : 1.0f - stPrev[2*tid + 1];

    float c0 = 0.0f, c1 = 0.0f;

#pragma unroll
    for (int i = 0; i < RPB; i++) {               // full unroll: d[] must stay in regs
        const float a_c = stCur[512 + i];
        float s0, s1;
        if (T == 0) {
            const float4 f = F[(size_t)(row0 + i) * (NN/2) + j];
            d0[i] = f.y - f.x;
            d1[i] = f.w - f.z;
            s0 = fsig(d0[i]);
            s1 = fsig(d1[i]);
        } else {
            const float m1 = w1 * stPrev[512 + i];
            s0 = fsig(d0[i] - m1 * bp0);
            s1 = fsig(d1[i] - m1 * bp1);
        }
        c0 += s0 * a_c;
        c1 += s1 * a_c;
        part[i * PSTR + tid] = s0 * wq0 + s1 * wq1;   // per-row partial, no shfl
        if (T == 4) {
            const float4 f = F[(size_t)(row0 + i) * (NN/2) + j];  // L3-resident
            const float mw = w1 * a_c;
            float4 o;
            o.x = f.x + mw * wq0; o.y = f.y;
            o.z = f.z + mw * wq1; o.w = f.w;
            outF[(size_t)(row0 + i) * (NN/2) + j] = o;
        }
    }

    // c: sliced far atomics (each address: 32 contributors)
    atomicAdd(&cout[(by & (NCSL-1))*ROWS + base + 2*j],     c0);
    atomicAdd(&cout[(by & (NCSL-1))*ROWS + base + 2*j + 1], c1);

    __syncthreads();
    // r: two-stage block reduce, then exclusive plain store (sx-sliced)
    {
        const int row = tid >> 4, seg = tid & 15;
        float s = 0.0f;
#pragma unroll
        for (int u = 0; u < 16; u++) s += part[row * PSTR + seg * 16 + u];
#pragma unroll
        for (int off = 8; off > 0; off >>= 1) s += __shfl_down(s, off, 16);
        if (seg == 0) rout[sx * ROWS + row0 + row] = s;
    }
}

// Fused persistent kernel: all 5 passes, grid-synced.  1024 blocks = 4/CU.
__global__ __launch_bounds__(256, 4) void kfused(
    const float4* __restrict__ F,
    const float2* __restrict__ S2, const float2* __restrict__ C2,
    const float* __restrict__ w,
    float* __restrict__ ws,
    float4* __restrict__ outF)
{
    __shared__ float st[3][528];       // rotating aS state
    __shared__ float sdif[528];        // S1-S0 (constant across passes)
    __shared__ float cdif[528];        // C0-C1 (constant across passes)
    __shared__ float part[16 * PSTR];

    const int tid  = threadIdx.x;
    const int sx   = blockIdx.x;          // 0..3  column split
    const int by   = blockIdx.y;          // 0..255 row group
    const int row0 = by * RPB;
    const int b    = by >> 7;             // batch
    const int bloc = by & 127;            // row group within batch
    const int base = b * NN;
    const float w0 = w[0], w1 = w[1];

    float d0[RPB], d1[RPB];               // register-resident F1-F0

    float* rb = ws;                               // 5 * 4*ROWS
    float* cb = ws + 5 * 4 * ROWS;                // 5 * 8*ROWS
    float* ab = ws + 5 * 4 * ROWS + 5 * 8 * ROWS; // 4 * ROWS (aS_1..aS_4)
#define RB(t) (rb + (t) * 4 * ROWS)
#define CB(t) (cb + (t) * (size_t)NCSL * ROWS)
#define AB(t) (ab + ((t) - 1) * ROWS)

    cg::grid_group grid = cg::this_grid();
#define GSYNC() do { __threadfence_system(); grid.sync(); __threadfence_system(); } while (0)

    do_pass<0>(st[0], st[2], st[1], sdif, cdif, part, d0, d1, F, S2, C2,
               nullptr, nullptr, RB(0), CB(0), nullptr, nullptr,
               tid, sx, by, bloc, row0, base, w0, w1);
    GSYNC();
    do_pass<1>(st[1], st[0], st[2], sdif, cdif, part, d0, d1, F, S2, C2,
               RB(0), CB(0), RB(1), CB(1), nullptr, nullptr,
               tid, sx, by, bloc, row0, base, w0, w1);
    GSYNC();
    do_pass<2>(st[2], st[1], st[0], sdif, cdif, part, d0, d1, F, S2, C2,
               RB(1), CB(1), RB(2), CB(2), nullptr, nullptr,
               tid, sx, by, bloc, row0, base, w0, w1);
    GSYNC();
    do_pass<3>(st[0], st[2], st[1], sdif, cdif, part, d0, d1, F, S2, C2,
               RB(2), CB(2), RB(3), CB(3), AB(3), nullptr,
               tid, sx, by, bloc, row0, base, w0, w1);
    GSYNC();
    do_pass<4>(st[1], st[0], st[2], sdif, cdif, part, d0, d1, F, S2, C2,
               RB(3), CB(3), RB(4), CB(4), AB(4), outF,
               tid, sx, by, bloc, row0, base, w0, w1);
#undef GSYNC
}

// ---------------------------------------------------------------------------
// Fallback path: the proven round-0 multi-launch kernel, verbatim.
// ---------------------------------------------------------------------------
template<int T>
__global__ __launch_bounds__(256) void kbig(
    const float4* __restrict__ F,
    const float2* __restrict__ S2, const float2* __restrict__ C2,
    const float* __restrict__ w,
    const float* __restrict__ rprev, const float* __restrict__ cprev,
    const float* __restrict__ aSm1, const float* __restrict__ aSm2,
    float* __restrict__ rout, float* __restrict__ cout,
    float* __restrict__ czero, float* __restrict__ aSout,
    float4* __restrict__ outF)
{
    __shared__ float sCur[528];
    __shared__ float sPrev[528];
    __shared__ float part[16 * PSTR];

    const int tid  = threadIdx.x;
    const int sx   = blockIdx.x;
    const int by   = blockIdx.y;
    const int row0 = by * RPB;
    const int b    = by >> 7;
    const int bloc = by & 127;
    const int base = b * NN;
    const float w0 = w[0], w1 = w[1];

    if (T < 4 && sx == 1) {
        int zi = by * 256 + tid;
        if (zi < NCSL * ROWS) czero[zi] = 0.0f;
    }

    for (int idx = tid; idx < 528; idx += 256) {
        int il = (idx < 512) ? (sx * 512 + idx) : (bloc * RPB + idx - 512);
        int g  = base + il;
        float2 sv = S2[g];
        float a0 = fsig(sv.y - sv.x);
        float cur, prev;
        if (T == 0) {
            cur = a0; prev = 0.0f;
        } else {
            float2 cv = C2[g];
            float rs = rprev[0*ROWS+g] + rprev[1*ROWS+g]
                     + rprev[2*ROWS+g] + rprev[3*ROWS+g];
            float cs = 0.0f;
#pragma unroll
            for (int s = 0; s < NCSL; s++) cs += cprev[s*ROWS + g];
            float qc;
            if (T == 1)      qc = fsig(cv.x - cv.y);
            else if (T == 2) qc = fsig(cv.x - cv.y - w0 * a0);
            else             qc = fsig(cv.x - cv.y - w0 * aSm2[g]);
            cur  = fsig((sv.y + w1*cs) - (sv.x + w0*qc + w1*rs));
            prev = (T == 1) ? a0 : aSm1[g];
        }
        sCur[idx]  = cur;
        sPrev[idx] = prev;
        if (T >= 1 && sx == 0 && idx >= 512) aSout[g] = cur;
    }
    __syncthreads();

    const int j = sx * 256 + tid;
    const float wq0 = 1.0f - sCur[2*tid];
    const float wq1 = 1.0f - sCur[2*tid + 1];
    const float bp0 = 1.0f - sPrev[2*tid];
    const float bp1 = 1.0f - sPrev[2*tid + 1];

    float c0 = 0.0f, c1 = 0.0f;

#pragma unroll 4
    for (int i = 0; i < RPB; i++) {
        const float a_c = sCur[512 + i];
        const float m1  = (T == 0) ? 0.0f : w1 * sPrev[512 + i];
        const float4 f = F[(size_t)(row0 + i) * (NN/2) + j];
        float s0 = fsig((f.y - f.x) - m1 * bp0);
        float s1 = fsig((f.w - f.z) - m1 * bp1);
        c0 += s0 * a_c;
        c1 += s1 * a_c;
        part[i * PSTR + tid] = s0 * wq0 + s1 * wq1;
        if (T == 4) {
            const float mw = w1 * a_c;
            float4 o;
            o.x = f.x + mw * wq0; o.y = f.y;
            o.z = f.z + mw * wq1; o.w = f.w;
            outF[(size_t)(row0 + i) * (NN/2) + j] = o;
        }
    }

    atomicAdd(&cout[(by & (NCSL-1))*ROWS + base + 2*j],     c0);
    atomicAdd(&cout[(by & (NCSL-1))*ROWS + base + 2*j + 1], c1);

    __syncthreads();
    {
        const int row = tid >> 4, seg = tid & 15;
        float s = 0.0f;
#pragma unroll
        for (int u = 0; u < 16; u++) s += part[row * PSTR + seg * 16 + u];
#pragma unroll
        for (int off = 8; off > 0; off >>= 1) s += __shfl_down(s, off, 16);
        if (seg == 0) rout[sx * ROWS + row0 + row] = s;
    }
}

// Epilogue: out_S, out_C from completed r_4, c_4, aS_4, aS_3.
__global__ void kfin(const float2* __restrict__ S2, const float2* __restrict__ C2,
                     const float* __restrict__ w,
                     const float* __restrict__ rpart, const float* __restrict__ cpart,
                     const float* __restrict__ aS4, const float* __restrict__ aS3,
                     float2* __restrict__ outS, float2* __restrict__ outC)
{
    int idx = blockIdx.x * blockDim.x + threadIdx.x;
    if (idx >= ROWS) return;
    float w0 = w[0], w1 = w[1];
    float rs = rpart[0*ROWS+idx] + rpart[1*ROWS+idx]
             + rpart[2*ROWS+idx] + rpart[3*ROWS+idx];
    float cs = 0.0f;
#pragma unroll
    for (int s = 0; s < NCSL; s++) cs += cpart[s*ROWS + idx];
    float2 sv = S2[idx], cv = C2[idx];
    float qc4 = fsig(cv.x - cv.y - w0 * aS3[idx]);
    float2 os, oc;
    os.x = sv.x + w0 * qc4 + w1 * rs;
    os.y = sv.y + w1 * cs;
    oc.x = cv.x;
    oc.y = cv.y + w0 * aS4[idx];
    outS[idx] = os;
    outC[idx] = oc;
}

extern "C" void kernel_launch(void* const* d_in, const int* in_sizes, int n_in,
                              void* d_out, int out_size, void* d_ws, size_t ws_size,
                              hipStream_t stream)
{
    const float2* S2 = (const float2*)d_in[0];
    const float2* C2 = (const float2*)d_in[1];
    const float4* F4 = (const float4*)d_in[2];
    const float*  w  = (const float*)d_in[3];
    float* out = (float*)d_out;
    float* ws  = (float*)d_ws;

    float* rb = ws;                               // 5 * 4*ROWS
    float* cb = ws + 5 * 4 * ROWS;                // 5 * 8*ROWS
    float* ab = ws + 5 * 4 * ROWS + 5 * 8 * ROWS; // 4 * ROWS
#define HRB(t) (rb + (t) * 4 * ROWS)
#define HCB(t) (cb + (t) * (size_t)NCSL * ROWS)
#define HAB(t) (ab + ((t) - 1) * ROWS)

    float* outS = out;
    float* outC = out + 2 * ROWS;
    float4* outF = (float4*)(out + 4 * ROWS);

    // pre-zero ALL c slices (fused path has no in-kernel czero)
    hipMemsetAsync(cb, 0, 5 * (size_t)NCSL * ROWS * sizeof(float), stream);

    dim3 gb(CSPLIT, NBY), bb(256, 1, 1);
    void* args[] = { (void*)&F4, (void*)&S2, (void*)&C2, (void*)&w,
                     (void*)&ws, (void*)&outF };
    hipError_t ce = hipLaunchCooperativeKernel((const void*)kfused, gb, bb,
                                               args, 0, stream);
    if (ce != hipSuccess) {
        // clear sticky error, run the proven multi-launch path
        (void)hipGetLastError();
        kbig<0><<<gb, bb, 0, stream>>>(F4, S2, C2, w, nullptr, nullptr, nullptr, nullptr,
                                       HRB(0), HCB(0), HCB(1), nullptr, nullptr);
        kbig<1><<<gb, bb, 0, stream>>>(F4, S2, C2, w, HRB(0), HCB(0), nullptr, nullptr,
                                       HRB(1), HCB(1), HCB(2), HAB(1), nullptr);
        kbig<2><<<gb, bb, 0, stream>>>(F4, S2, C2, w, HRB(1), HCB(1), HAB(1), nullptr,
                                       HRB(2), HCB(2), HCB(3), HAB(2), nullptr);
        kbig<3><<<gb, bb, 0, stream>>>(F4, S2, C2, w, HRB(2), HCB(2), HAB(2), HAB(1),
                                       HRB(3), HCB(3), HCB(4), HAB(3), nullptr);
        kbig<4><<<gb, bb, 0, stream>>>(F4, S2, C2, w, HRB(3), HCB(3), HAB(3), HAB(2),
                                       HRB(4), HCB(4), nullptr, HAB(4), outF);
    }
    kfin<<<dim3(ROWS/256), bb, 0, stream>>>(S2, C2, w, HRB(4), HCB(4), HAB(4), HAB(3),
                                            (float2*)outS, (float2*)outC);
}

// Round 3
// 458.963 us; speedup vs baseline: 2.4427x; 2.4427x over previous
//
#include <hip/hip_runtime.h>

#define NN   2048
#define ROWS 4096          // B*N
#define RPB  16            // rows per block
#define CSPLIT 4           // column splits; block covers 256 float4 cols
#define NBY  (ROWS/RPB)    // 256
#define NCSL 8             // c-accumulator slices
#define PSTR 257           // LDS partial stride
#define NBLK (CSPLIT*NBY)  // 1024 blocks = 4/CU on 256 CUs

__device__ __forceinline__ float fsig(float x) {
    float e = __expf(-x);
    return __builtin_amdgcn_rcpf(1.0f + e);
}

// Device-scope (agent) relaxed atomics: cross-XCD-coherent data path.
// All cross-pass workspace traffic goes through these, so correctness never
// depends on per-wave L2 writeback fences (round-2's 1000us mistake).
__device__ __forceinline__ float gload(const float* p) {
    return __hip_atomic_load(p, __ATOMIC_RELAXED, __HIP_MEMORY_SCOPE_AGENT);
}
__device__ __forceinline__ void gstore(float* p, float v) {
    __hip_atomic_store(p, v, __ATOMIC_RELAXED, __HIP_MEMORY_SCOPE_AGENT);
}

// Lightweight grid barrier: one release-RMW arrive per block + relaxed spin
// + single acquire edge.  HB chain: data relaxed-store -> __syncthreads
// (drains vmcnt before s_barrier) -> release-arrive -> acquire-load ->
// __syncthreads -> data relaxed-load.  No per-wave fences at all.
__device__ __forceinline__ void gridbar(int* cnt) {
    __syncthreads();
    if (threadIdx.x == 0) {
        __hip_atomic_fetch_add(cnt, 1, __ATOMIC_ACQ_REL, __HIP_MEMORY_SCOPE_AGENT);
        while (__hip_atomic_load(cnt, __ATOMIC_RELAXED, __HIP_MEMORY_SCOPE_AGENT) < NBLK)
            __builtin_amdgcn_s_sleep(2);
        (void)__hip_atomic_load(cnt, __ATOMIC_ACQUIRE, __HIP_MEMORY_SCOPE_AGENT);
    }
    __syncthreads();
}

// ---------------------------------------------------------------------------
// Fused-path pass body.  CB slices are host-pre-zeroed.
// stCur/stPrev/stPP: rotating LDS aS state (aS_T / aS_{T-1} / aS_{T-2}).
// d0/d1: register-resident F1-F0 (constant across passes, filled at T==0).
// ---------------------------------------------------------------------------
template<int T>
__device__ __forceinline__ void do_pass(
    float* __restrict__ stCur, const float* __restrict__ stPrev,
    const float* __restrict__ stPP,
    float* __restrict__ sdif, float* __restrict__ cdif,
    float* __restrict__ part,
    float (&d0)[RPB], float (&d1)[RPB],
    const float4* __restrict__ F,
    const float2* __restrict__ S2, const float2* __restrict__ C2,
    const float* __restrict__ rprev, const float* __restrict__ cprev,
    float* __restrict__ rout, float* __restrict__ cout,
    float* __restrict__ aSout, float4* __restrict__ outF,
    int tid, int sx, int by, int bloc, int row0, int base,
    float w0, float w1)
{
    // ---- prologue: state for the 528 indices this block touches ----
    for (int idx = tid; idx < 528; idx += 256) {
        int il = (idx < 512) ? (sx * 512 + idx) : (bloc * RPB + idx - 512);
        int g  = base + il;
        float cur;
        if (T == 0) {
            float2 sv = S2[g], cv = C2[g];
            float sd = sv.y - sv.x;
            sdif[idx] = sd;
            cdif[idx] = cv.x - cv.y;
            cur = fsig(sd);                       // aS_0
        } else {
            float rs = gload(rprev + 0*ROWS + g) + gload(rprev + 1*ROWS + g)
                     + gload(rprev + 2*ROWS + g) + gload(rprev + 3*ROWS + g);
            float cs = 0.0f;
#pragma unroll
            for (int s = 0; s < NCSL; s++) cs += gload(cprev + s*ROWS + g);
            float qc = (T == 1) ? fsig(cdif[idx])                      // qC0_0
                                : fsig(cdif[idx] - w0 * stPP[idx]);    // qC0_{T-1}
            cur = fsig(sdif[idx] + w1*cs - w0*qc - w1*rs);             // aS_T
        }
        stCur[idx] = cur;
        if (T >= 3 && sx == 0 && idx >= 512) gstore(aSout + g, cur);   // aS_3/aS_4
    }
    __syncthreads();

    const int j = sx * 256 + tid;                  // float4 column
    const float wq0 = 1.0f - stCur[2*tid];
    const float wq1 = 1.0f - stCur[2*tid + 1];
    const float bp0 = (T == 0) ? 0.0f : 1.0f - stPrev[2*tid];
    const float bp1 = (T == 0) ? 0.0f : 1.0f - stPrev[2*tid + 1];

    float c0 = 0.0f, c1 = 0.0f;

#pragma unroll
    for (int i = 0; i < RPB; i++) {               // full unroll: d[] must stay in regs
        const float a_c = stCur[512 + i];
        float s0, s1;
        if (T == 0) {
            const float4 f = F[(size_t)(row0 + i) * (NN/2) + j];
            d0[i] = f.y - f.x;
            d1[i] = f.w - f.z;
            s0 = fsig(d0[i]);
            s1 = fsig(d1[i]);
        } else {
            const float m1 = w1 * stPrev[512 + i];
            s0 = fsig(d0[i] - m1 * bp0);
            s1 = fsig(d1[i] - m1 * bp1);
        }
        c0 += s0 * a_c;
        c1 += s1 * a_c;
        part[i * PSTR + tid] = s0 * wq0 + s1 * wq1;   // per-row partial, no shfl
        if (T == 4) {
            const float4 f = F[(size_t)(row0 + i) * (NN/2) + j];  // L3-resident
            const float mw = w1 * a_c;
            float4 o;
            o.x = f.x + mw * wq0; o.y = f.y;
            o.z = f.z + mw * wq1; o.w = f.w;
            outF[(size_t)(row0 + i) * (NN/2) + j] = o;
        }
    }

    // c: sliced far atomics, device-scope by default (cross-XCD coherent)
    atomicAdd(&cout[(by & (NCSL-1))*ROWS + base + 2*j],     c0);
    atomicAdd(&cout[(by & (NCSL-1))*ROWS + base + 2*j + 1], c1);

    __syncthreads();
    // r: two-stage block reduce, then exclusive agent-scope store (sx-sliced)
    {
        const int row = tid >> 4, seg = tid & 15;
        float s = 0.0f;
#pragma unroll
        for (int u = 0; u < 16; u++) s += part[row * PSTR + seg * 16 + u];
#pragma unroll
        for (int off = 8; off > 0; off >>= 1) s += __shfl_down(s, off, 16);
        if (seg == 0) gstore(rout + sx * ROWS + row0 + row, s);
    }
}

// Fused persistent kernel: all 5 passes, custom grid barrier.  1024 blocks.
__global__ __launch_bounds__(256, 4) void kfused(
    const float4* __restrict__ F,
    const float2* __restrict__ S2, const float2* __restrict__ C2,
    const float* __restrict__ w,
    float* __restrict__ ws,
    float4* __restrict__ outF)
{
    __shared__ float st[3][528];       // rotating aS state
    __shared__ float sdif[528];        // S1-S0 (constant across passes)
    __shared__ float cdif[528];        // C0-C1 (constant across passes)
    __shared__ float part[16 * PSTR];

    const int tid  = threadIdx.x;
    const int sx   = blockIdx.x;          // 0..3  column split
    const int by   = blockIdx.y;          // 0..255 row group
    const int row0 = by * RPB;
    const int b    = by >> 7;             // batch
    const int bloc = by & 127;            // row group within batch
    const int base = b * NN;
    const float w0 = w[0], w1 = w[1];

    float d0[RPB], d1[RPB];               // register-resident F1-F0

    float* rb = ws;                               // 5 * 4*ROWS
    float* cb = ws + 5 * 4 * ROWS;                // 5 * 8*ROWS
    float* ab = ws + 5 * 4 * ROWS + 5 * 8 * ROWS; // 4 * ROWS (aS_1..aS_4)
    int*   bar = (int*)ab;   // barrier counters live in AB(1) (unused by fused path)
#define RB(t) (rb + (t) * 4 * ROWS)
#define CB(t) (cb + (t) * (size_t)NCSL * ROWS)
#define AB(t) (ab + ((t) - 1) * ROWS)

    do_pass<0>(st[0], st[2], st[1], sdif, cdif, part, d0, d1, F, S2, C2,
               nullptr, nullptr, RB(0), CB(0), nullptr, nullptr,
               tid, sx, by, bloc, row0, base, w0, w1);
    gridbar(bar + 0);
    do_pass<1>(st[1], st[0], st[2], sdif, cdif, part, d0, d1, F, S2, C2,
               RB(0), CB(0), RB(1), CB(1), nullptr, nullptr,
               tid, sx, by, bloc, row0, base, w0, w1);
    gridbar(bar + 1);
    do_pass<2>(st[2], st[1], st[0], sdif, cdif, part, d0, d1, F, S2, C2,
               RB(1), CB(1), RB(2), CB(2), nullptr, nullptr,
               tid, sx, by, bloc, row0, base, w0, w1);
    gridbar(bar + 2);
    do_pass<3>(st[0], st[2], st[1], sdif, cdif, part, d0, d1, F, S2, C2,
               RB(2), CB(2), RB(3), CB(3), AB(3), nullptr,
               tid, sx, by, bloc, row0, base, w0, w1);
    gridbar(bar + 3);
    do_pass<4>(st[1], st[0], st[2], sdif, cdif, part, d0, d1, F, S2, C2,
               RB(3), CB(3), RB(4), CB(4), AB(4), outF,
               tid, sx, by, bloc, row0, base, w0, w1);
}

// ---------------------------------------------------------------------------
// Fallback path: the proven round-0 multi-launch kernel, verbatim.
// ---------------------------------------------------------------------------
template<int T>
__global__ __launch_bounds__(256) void kbig(
    const float4* __restrict__ F,
    const float2* __restrict__ S2, const float2* __restrict__ C2,
    const float* __restrict__ w,
    const float* __restrict__ rprev, const float* __restrict__ cprev,
    const float* __restrict__ aSm1, const float* __restrict__ aSm2,
    float* __restrict__ rout, float* __restrict__ cout,
    float* __restrict__ czero, float* __restrict__ aSout,
    float4* __restrict__ outF)
{
    __shared__ float sCur[528];
    __shared__ float sPrev[528];
    __shared__ float part[16 * PSTR];

    const int tid  = threadIdx.x;
    const int sx   = blockIdx.x;
    const int by   = blockIdx.y;
    const int row0 = by * RPB;
    const int b    = by >> 7;
    const int bloc = by & 127;
    const int base = b * NN;
    const float w0 = w[0], w1 = w[1];

    if (T < 4 && sx == 1) {
        int zi = by * 256 + tid;
        if (zi < NCSL * ROWS) czero[zi] = 0.0f;
    }

    for (int idx = tid; idx < 528; idx += 256) {
        int il = (idx < 512) ? (sx * 512 + idx) : (bloc * RPB + idx - 512);
        int g  = base + il;
        float2 sv = S2[g];
        float a0 = fsig(sv.y - sv.x);
        float cur, prev;
        if (T == 0) {
            cur = a0; prev = 0.0f;
        } else {
            float2 cv = C2[g];
            float rs = rprev[0*ROWS+g] + rprev[1*ROWS+g]
                     + rprev[2*ROWS+g] + rprev[3*ROWS+g];
            float cs = 0.0f;
#pragma unroll
            for (int s = 0; s < NCSL; s++) cs += cprev[s*ROWS + g];
            float qc;
            if (T == 1)      qc = fsig(cv.x - cv.y);
            else if (T == 2) qc = fsig(cv.x - cv.y - w0 * a0);
            else             qc = fsig(cv.x - cv.y - w0 * aSm2[g]);
            cur  = fsig((sv.y + w1*cs) - (sv.x + w0*qc + w1*rs));
            prev = (T == 1) ? a0 : aSm1[g];
        }
        sCur[idx]  = cur;
        sPrev[idx] = prev;
        if (T >= 1 && sx == 0 && idx >= 512) aSout[g] = cur;
    }
    __syncthreads();

    const int j = sx * 256 + tid;
    const float wq0 = 1.0f - sCur[2*tid];
    const float wq1 = 1.0f - sCur[2*tid + 1];
    const float bp0 = 1.0f - sPrev[2*tid];
    const float bp1 = 1.0f - sPrev[2*tid + 1];

    float c0 = 0.0f, c1 = 0.0f;

#pragma unroll 4
    for (int i = 0; i < RPB; i++) {
        const float a_c = sCur[512 + i];
        const float m1  = (T == 0) ? 0.0f : w1 * sPrev[512 + i];
        const float4 f = F[(size_t)(row0 + i) * (NN/2) + j];
        float s0 = fsig((f.y - f.x) - m1 * bp0);
        float s1 = fsig((f.w - f.z) - m1 * bp1);
        c0 += s0 * a_c;
        c1 += s1 * a_c;
        part[i * PSTR + tid] = s0 * wq0 + s1 * wq1;
        if (T == 4) {
            const float mw = w1 * a_c;
            float4 o;
            o.x = f.x + mw * wq0; o.y = f.y;
            o.z = f.z + mw * wq1; o.w = f.w;
            outF[(size_t)(row0 + i) * (NN/2) + j] = o;
        }
    }

    atomicAdd(&cout[(by & (NCSL-1))*ROWS + base + 2*j],     c0);
    atomicAdd(&cout[(by & (NCSL-1))*ROWS + base + 2*j + 1], c1);

    __syncthreads();
    {
        const int row = tid >> 4, seg = tid & 15;
        float s = 0.0f;
#pragma unroll
        for (int u = 0; u < 16; u++) s += part[row * PSTR + seg * 16 + u];
#pragma unroll
        for (int off = 8; off > 0; off >>= 1) s += __shfl_down(s, off, 16);
        if (seg == 0) rout[sx * ROWS + row0 + row] = s;
    }
}

// Epilogue: out_S, out_C from completed r_4, c_4, aS_4, aS_3.
__global__ void kfin(const float2* __restrict__ S2, const float2* __restrict__ C2,
                     const float* __restrict__ w,
                     const float* __restrict__ rpart, const float* __restrict__ cpart,
                     const float* __restrict__ aS4, const float* __restrict__ aS3,
                     float2* __restrict__ outS, float2* __restrict__ outC)
{
    int idx = blockIdx.x * blockDim.x + threadIdx.x;
    if (idx >= ROWS) return;
    float w0 = w[0], w1 = w[1];
    float rs = rpart[0*ROWS+idx] + rpart[1*ROWS+idx]
             + rpart[2*ROWS+idx] + rpart[3*ROWS+idx];
    float cs = 0.0f;
#pragma unroll
    for (int s = 0; s < NCSL; s++) cs += cpart[s*ROWS + idx];
    float2 sv = S2[idx], cv = C2[idx];
    float qc4 = fsig(cv.x - cv.y - w0 * aS3[idx]);
    float2 os, oc;
    os.x = sv.x + w0 * qc4 + w1 * rs;
    os.y = sv.y + w1 * cs;
    oc.x = cv.x;
    oc.y = cv.y + w0 * aS4[idx];
    outS[idx] = os;
    outC[idx] = oc;
}

extern "C" void kernel_launch(void* const* d_in, const int* in_sizes, int n_in,
                              void* d_out, int out_size, void* d_ws, size_t ws_size,
                              hipStream_t stream)
{
    const float2* S2 = (const float2*)d_in[0];
    const float2* C2 = (const float2*)d_in[1];
    const float4* F4 = (const float4*)d_in[2];
    const float*  w  = (const float*)d_in[3];
    float* out = (float*)d_out;
    float* ws  = (float*)d_ws;

    float* rb = ws;                               // 5 * 4*ROWS
    float* cb = ws + 5 * 4 * ROWS;                // 5 * 8*ROWS
    float* ab = ws + 5 * 4 * ROWS + 5 * 8 * ROWS; // 4 * ROWS
#define HRB(t) (rb + (t) * 4 * ROWS)
#define HCB(t) (cb + (t) * (size_t)NCSL * ROWS)
#define HAB(t) (ab + ((t) - 1) * ROWS)

    float* outS = out;
    float* outC = out + 2 * ROWS;
    float4* outF = (float4*)(out + 4 * ROWS);

    // pre-zero ALL c slices + the 4 barrier counters (at ab[0..3], in-graph so
    // they reset every replay)
    hipMemsetAsync(cb, 0, 5 * (size_t)NCSL * ROWS * sizeof(float), stream);
    hipMemsetAsync(ab, 0, 4 * sizeof(int), stream);

    dim3 gb(CSPLIT, NBY), bb(256, 1, 1);
    void* args[] = { (void*)&F4, (void*)&S2, (void*)&C2, (void*)&w,
                     (void*)&ws, (void*)&outF };
    hipError_t ce = hipLaunchCooperativeKernel((const void*)kfused, gb, bb,
                                               args, 0, stream);
    if (ce != hipSuccess) {
        // clear sticky error, run the proven multi-launch path
        (void)hipGetLastError();
        kbig<0><<<gb, bb, 0, stream>>>(F4, S2, C2, w, nullptr, nullptr, nullptr, nullptr,
                                       HRB(0), HCB(0), HCB(1), nullptr, nullptr);
        kbig<1><<<gb, bb, 0, stream>>>(F4, S2, C2, w, HRB(0), HCB(0), nullptr, nullptr,
                                       HRB(1), HCB(1), HCB(2), HAB(1), nullptr);
        kbig<2><<<gb, bb, 0, stream>>>(F4, S2, C2, w, HRB(1), HCB(1), HAB(1), nullptr,
                                       HRB(2), HCB(2), HCB(3), HAB(2), nullptr);
        kbig<3><<<gb, bb, 0, stream>>>(F4, S2, C2, w, HRB(2), HCB(2), HAB(2), HAB(1),
                                       HRB(3), HCB(3), HCB(4), HAB(3), nullptr);
        kbig<4><<<gb, bb, 0, stream>>>(F4, S2, C2, w, HRB(3), HCB(3), HAB(3), HAB(2),
                                       HRB(4), HCB(4), nullptr, HAB(4), outF);
    }
    kfin<<<dim3(ROWS/256), bb, 0, stream>>>(S2, C2, w, HRB(4), HCB(4), HAB(4), HAB(3),
                                            (float2*)outS, (float2*)outC);
}

// Round 4
// 207.851 us; speedup vs baseline: 5.3938x; 2.2081x over previous
//
#include <hip/hip_runtime.h>

#define NN   2048
#define ROWS 4096          // B*N
#define RPB  16            // rows per block
#define CSPLIT 4           // column splits; block covers 256 float4 cols
#define NBY  (ROWS/RPB)    // 256
#define NCSL 8             // c-accumulator slices
#define PSTR 257           // LDS partial stride
#define NBLK (CSPLIT*NBY)  // 1024 blocks = 4/CU on 256 CUs

#define SUBW 32            // arrivals per sub-counter
#define NSUB (NBLK/SUBW)   // 32 sub-counters
#define CPAD 16            // ints per counter (64B padding)
#define BARSTRIDE ((NSUB+1)*CPAD)   // ints per barrier instance

__device__ __forceinline__ float fsig(float x) {
    float e = __expf(-x);
    return __builtin_amdgcn_rcpf(1.0f + e);
}

// Agent-scope relaxed atomics: cross-XCD-coherent data path.  sc1 loads/stores
// bypass the non-coherent per-XCD L1/L2 and hit the coherence point directly,
// so NO fence/writeback/invalidate is ever needed for cross-pass data.
__device__ __forceinline__ float gload(const float* p) {
    return __hip_atomic_load(p, __ATOMIC_RELAXED, __HIP_MEMORY_SCOPE_AGENT);
}
__device__ __forceinline__ void gstore(float* p, float v) {
    __hip_atomic_store(p, v, __ATOMIC_RELAXED, __HIP_MEMORY_SCOPE_AGENT);
}

// Fully-relaxed two-level grid barrier.
// Round-3 lesson: agent-scope ACQ_REL RMW emits buffer_wbl2 (full L2 writeback)
// and the acquire emits buffer_inv — ~80us/barrier across 1024 blocks.  Since
// ALL cross-pass data is sc1 (never L2-resident), relaxed ordering suffices:
// __syncthreads drains vmcnt(0) (all sc1 stores+atomics at coherence point)
// before thread 0 arrives; readers' sc1 loads always fetch from the CP.
// Two-level sharding (32 sub-counters -> root) avoids 1024 serialized RMWs
// on one cacheline.
__device__ __forceinline__ void gridbar(int* cnt, int bid) {
    __syncthreads();                      // emits s_waitcnt vmcnt(0) + s_barrier
    if (threadIdx.x == 0) {
        asm volatile("" ::: "memory");    // pin program order (no runtime cost)
        int* sub  = cnt + (bid & (NSUB - 1)) * CPAD;
        int* root = cnt + NSUB * CPAD;
        int old = __hip_atomic_fetch_add(sub, 1, __ATOMIC_RELAXED,
                                         __HIP_MEMORY_SCOPE_AGENT);
        if (old == SUBW - 1)
            __hip_atomic_fetch_add(root, 1, __ATOMIC_RELAXED,
                                   __HIP_MEMORY_SCOPE_AGENT);
        while (__hip_atomic_load(root, __ATOMIC_RELAXED,
                                 __HIP_MEMORY_SCOPE_AGENT) < NSUB)
            __builtin_amdgcn_s_sleep(1);
        asm volatile("" ::: "memory");
    }
    __syncthreads();
}

// ---------------------------------------------------------------------------
// Fused-path pass body.  CB slices are host-pre-zeroed.
// stCur/stPrev/stPP: rotating LDS aS state (aS_T / aS_{T-1} / aS_{T-2}).
// d0/d1: register-resident F1-F0 (constant across passes, filled at T==0).
// ---------------------------------------------------------------------------
template<int T>
__device__ __forceinline__ void do_pass(
    float* __restrict__ stCur, const float* __restrict__ stPrev,
    const float* __restrict__ stPP,
    float* __restrict__ sdif, float* __restrict__ cdif,
    float* __restrict__ part,
    float (&d0)[RPB], float (&d1)[RPB],
    const float4* __restrict__ F,
    const float2* __restrict__ S2, const float2* __restrict__ C2,
    const float* __restrict__ rprev, const float* __restrict__ cprev,
    float* __restrict__ rout, float* __restrict__ cout,
    float* __restrict__ aSout, float4* __restrict__ outF,
    int tid, int sx, int by, int bloc, int row0, int base,
    float w0, float w1)
{
    // ---- prologue: state for the 528 indices this block touches ----
    for (int idx = tid; idx < 528; idx += 256) {
        int il = (idx < 512) ? (sx * 512 + idx) : (bloc * RPB + idx - 512);
        int g  = base + il;
        float cur;
        if (T == 0) {
            float2 sv = S2[g], cv = C2[g];
            float sd = sv.y - sv.x;
            sdif[idx] = sd;
            cdif[idx] = cv.x - cv.y;
            cur = fsig(sd);                       // aS_0
        } else {
            float rs = gload(rprev + 0*ROWS + g) + gload(rprev + 1*ROWS + g)
                     + gload(rprev + 2*ROWS + g) + gload(rprev + 3*ROWS + g);
            float cs = 0.0f;
#pragma unroll
            for (int s = 0; s < NCSL; s++) cs += gload(cprev + s*ROWS + g);
            float qc = (T == 1) ? fsig(cdif[idx])                      // qC0_0
                                : fsig(cdif[idx] - w0 * stPP[idx]);    // qC0_{T-1}
            cur = fsig(sdif[idx] + w1*cs - w0*qc - w1*rs);             // aS_T
        }
        stCur[idx] = cur;
        if (T >= 3 && sx == 0 && idx >= 512) gstore(aSout + g, cur);   // aS_3/aS_4
    }
    __syncthreads();

    const int j = sx * 256 + tid;                  // float4 column
    const float wq0 = 1.0f - stCur[2*tid];
    const float wq1 = 1.0f - stCur[2*tid + 1];
    const float bp0 = (T == 0) ? 0.0f : 1.0f - stPrev[2*tid];
    const float bp1 = (T == 0) ? 0.0f : 1.0f - stPrev[2*tid + 1];

    float c0 = 0.0f, c1 = 0.0f;

#pragma unroll
    for (int i = 0; i < RPB; i++) {               // full unroll: d[] must stay in regs
        const float a_c = stCur[512 + i];
        float s0, s1;
        if (T == 0) {
            const float4 f = F[(size_t)(row0 + i) * (NN/2) + j];
            d0[i] = f.y - f.x;
            d1[i] = f.w - f.z;
            s0 = fsig(d0[i]);
            s1 = fsig(d1[i]);
        } else {
            const float m1 = w1 * stPrev[512 + i];
            s0 = fsig(d0[i] - m1 * bp0);
            s1 = fsig(d1[i] - m1 * bp1);
        }
        c0 += s0 * a_c;
        c1 += s1 * a_c;
        part[i * PSTR + tid] = s0 * wq0 + s1 * wq1;   // per-row partial, no shfl
        if (T == 4) {
            const float4 f = F[(size_t)(row0 + i) * (NN/2) + j];  // L3-resident
            const float mw = w1 * a_c;
            float4 o;
            o.x = f.x + mw * wq0; o.y = f.y;
            o.z = f.z + mw * wq1; o.w = f.w;
            outF[(size_t)(row0 + i) * (NN/2) + j] = o;
        }
    }

    // c: sliced far atomics, relaxed agent scope (execute at coherence point)
    atomicAdd(&cout[(by & (NCSL-1))*ROWS + base + 2*j],     c0);
    atomicAdd(&cout[(by & (NCSL-1))*ROWS + base + 2*j + 1], c1);

    __syncthreads();
    // r: two-stage block reduce, then exclusive agent-scope store (sx-sliced)
    {
        const int row = tid >> 4, seg = tid & 15;
        float s = 0.0f;
#pragma unroll
        for (int u = 0; u < 16; u++) s += part[row * PSTR + seg * 16 + u];
#pragma unroll
        for (int off = 8; off > 0; off >>= 1) s += __shfl_down(s, off, 16);
        if (seg == 0) gstore(rout + sx * ROWS + row0 + row, s);
    }
}

// Fused persistent kernel: all 5 passes, relaxed two-level grid barrier.
__global__ __launch_bounds__(256, 4) void kfused(
    const float4* __restrict__ F,
    const float2* __restrict__ S2, const float2* __restrict__ C2,
    const float* __restrict__ w,
    float* __restrict__ ws,
    float4* __restrict__ outF)
{
    __shared__ float st[3][528];       // rotating aS state
    __shared__ float sdif[528];        // S1-S0 (constant across passes)
    __shared__ float cdif[528];        // C0-C1 (constant across passes)
    __shared__ float part[16 * PSTR];

    const int tid  = threadIdx.x;
    const int sx   = blockIdx.x;          // 0..3  column split
    const int by   = blockIdx.y;          // 0..255 row group
    const int row0 = by * RPB;
    const int b    = by >> 7;             // batch
    const int bloc = by & 127;            // row group within batch
    const int base = b * NN;
    const int bid  = by * CSPLIT + sx;    // linear block id
    const float w0 = w[0], w1 = w[1];

    float d0[RPB], d1[RPB];               // register-resident F1-F0

    float* rb = ws;                               // 5 * 4*ROWS
    float* cb = ws + 5 * 4 * ROWS;                // 5 * 8*ROWS
    float* ab = ws + 5 * 4 * ROWS + 5 * 8 * ROWS; // 4 * ROWS (aS_1..aS_4)
    int*   bar = (int*)ab;   // barrier counters in ab[0..2*ROWS) (unused by fused)
#define RB(t) (rb + (t) * 4 * ROWS)
#define CB(t) (cb + (t) * (size_t)NCSL * ROWS)
#define AB(t) (ab + ((t) - 1) * ROWS)

    do_pass<0>(st[0], st[2], st[1], sdif, cdif, part, d0, d1, F, S2, C2,
               nullptr, nullptr, RB(0), CB(0), nullptr, nullptr,
               tid, sx, by, bloc, row0, base, w0, w1);
    gridbar(bar + 0*BARSTRIDE, bid);
    do_pass<1>(st[1], st[0], st[2], sdif, cdif, part, d0, d1, F, S2, C2,
               RB(0), CB(0), RB(1), CB(1), nullptr, nullptr,
               tid, sx, by, bloc, row0, base, w0, w1);
    gridbar(bar + 1*BARSTRIDE, bid);
    do_pass<2>(st[2], st[1], st[0], sdif, cdif, part, d0, d1, F, S2, C2,
               RB(1), CB(1), RB(2), CB(2), nullptr, nullptr,
               tid, sx, by, bloc, row0, base, w0, w1);
    gridbar(bar + 2*BARSTRIDE, bid);
    do_pass<3>(st[0], st[2], st[1], sdif, cdif, part, d0, d1, F, S2, C2,
               RB(2), CB(2), RB(3), CB(3), AB(3), nullptr,
               tid, sx, by, bloc, row0, base, w0, w1);
    gridbar(bar + 3*BARSTRIDE, bid);
    do_pass<4>(st[1], st[0], st[2], sdif, cdif, part, d0, d1, F, S2, C2,
               RB(3), CB(3), RB(4), CB(4), AB(4), outF,
               tid, sx, by, bloc, row0, base, w0, w1);
}

// ---------------------------------------------------------------------------
// Fallback path: the proven round-0 multi-launch kernel, verbatim.
// ---------------------------------------------------------------------------
template<int T>
__global__ __launch_bounds__(256) void kbig(
    const float4* __restrict__ F,
    const float2* __restrict__ S2, const float2* __restrict__ C2,
    const float* __restrict__ w,
    const float* __restrict__ rprev, const float* __restrict__ cprev,
    const float* __restrict__ aSm1, const float* __restrict__ aSm2,
    float* __restrict__ rout, float* __restrict__ cout,
    float* __restrict__ czero, float* __restrict__ aSout,
    float4* __restrict__ outF)
{
    __shared__ float sCur[528];
    __shared__ float sPrev[528];
    __shared__ float part[16 * PSTR];

    const int tid  = threadIdx.x;
    const int sx   = blockIdx.x;
    const int by   = blockIdx.y;
    const int row0 = by * RPB;
    const int b    = by >> 7;
    const int bloc = by & 127;
    const int base = b * NN;
    const float w0 = w[0], w1 = w[1];

    if (T < 4 && sx == 1) {
        int zi = by * 256 + tid;
        if (zi < NCSL * ROWS) czero[zi] = 0.0f;
    }

    for (int idx = tid; idx < 528; idx += 256) {
        int il = (idx < 512) ? (sx * 512 + idx) : (bloc * RPB + idx - 512);
        int g  = base + il;
        float2 sv = S2[g];
        float a0 = fsig(sv.y - sv.x);
        float cur, prev;
        if (T == 0) {
            cur = a0; prev = 0.0f;
        } else {
            float2 cv = C2[g];
            float rs = rprev[0*ROWS+g] + rprev[1*ROWS+g]
                     + rprev[2*ROWS+g] + rprev[3*ROWS+g];
            float cs = 0.0f;
#pragma unroll
            for (int s = 0; s < NCSL; s++) cs += cprev[s*ROWS + g];
            float qc;
            if (T == 1)      qc = fsig(cv.x - cv.y);
            else if (T == 2) qc = fsig(cv.x - cv.y - w0 * a0);
            else             qc = fsig(cv.x - cv.y - w0 * aSm2[g]);
            cur  = fsig((sv.y + w1*cs) - (sv.x + w0*qc + w1*rs));
            prev = (T == 1) ? a0 : aSm1[g];
        }
        sCur[idx]  = cur;
        sPrev[idx] = prev;
        if (T >= 1 && sx == 0 && idx >= 512) aSout[g] = cur;
    }
    __syncthreads();

    const int j = sx * 256 + tid;
    const float wq0 = 1.0f - sCur[2*tid];
    const float wq1 = 1.0f - sCur[2*tid + 1];
    const float bp0 = 1.0f - sPrev[2*tid];
    const float bp1 = 1.0f - sPrev[2*tid + 1];

    float c0 = 0.0f, c1 = 0.0f;

#pragma unroll 4
    for (int i = 0; i < RPB; i++) {
        const float a_c = sCur[512 + i];
        const float m1  = (T == 0) ? 0.0f : w1 * sPrev[512 + i];
        const float4 f = F[(size_t)(row0 + i) * (NN/2) + j];
        float s0 = fsig((f.y - f.x) - m1 * bp0);
        float s1 = fsig((f.w - f.z) - m1 * bp1);
        c0 += s0 * a_c;
        c1 += s1 * a_c;
        part[i * PSTR + tid] = s0 * wq0 + s1 * wq1;
        if (T == 4) {
            const float mw = w1 * a_c;
            float4 o;
            o.x = f.x + mw * wq0; o.y = f.y;
            o.z = f.z + mw * wq1; o.w = f.w;
            outF[(size_t)(row0 + i) * (NN/2) + j] = o;
        }
    }

    atomicAdd(&cout[(by & (NCSL-1))*ROWS + base + 2*j],     c0);
    atomicAdd(&cout[(by & (NCSL-1))*ROWS + base + 2*j + 1], c1);

    __syncthreads();
    {
        const int row = tid >> 4, seg = tid & 15;
        float s = 0.0f;
#pragma unroll
        for (int u = 0; u < 16; u++) s += part[row * PSTR + seg * 16 + u];
#pragma unroll
        for (int off = 8; off > 0; off >>= 1) s += __shfl_down(s, off, 16);
        if (seg == 0) rout[sx * ROWS + row0 + row] = s;
    }
}

// Epilogue: out_S, out_C from completed r_4, c_4, aS_4, aS_3.
__global__ void kfin(const float2* __restrict__ S2, const float2* __restrict__ C2,
                     const float* __restrict__ w,
                     const float* __restrict__ rpart, const float* __restrict__ cpart,
                     const float* __restrict__ aS4, const float* __restrict__ aS3,
                     float2* __restrict__ outS, float2* __restrict__ outC)
{
    int idx = blockIdx.x * blockDim.x + threadIdx.x;
    if (idx >= ROWS) return;
    float w0 = w[0], w1 = w[1];
    float rs = rpart[0*ROWS+idx] + rpart[1*ROWS+idx]
             + rpart[2*ROWS+idx] + rpart[3*ROWS+idx];
    float cs = 0.0f;
#pragma unroll
    for (int s = 0; s < NCSL; s++) cs += cpart[s*ROWS + idx];
    float2 sv = S2[idx], cv = C2[idx];
    float qc4 = fsig(cv.x - cv.y - w0 * aS3[idx]);
    float2 os, oc;
    os.x = sv.x + w0 * qc4 + w1 * rs;
    os.y = sv.y + w1 * cs;
    oc.x = cv.x;
    oc.y = cv.y + w0 * aS4[idx];
    outS[idx] = os;
    outC[idx] = oc;
}

extern "C" void kernel_launch(void* const* d_in, const int* in_sizes, int n_in,
                              void* d_out, int out_size, void* d_ws, size_t ws_size,
                              hipStream_t stream)
{
    const float2* S2 = (const float2*)d_in[0];
    const float2* C2 = (const float2*)d_in[1];
    const float4* F4 = (const float4*)d_in[2];
    const float*  w  = (const float*)d_in[3];
    float* out = (float*)d_out;
    float* ws  = (float*)d_ws;

    float* rb = ws;                               // 5 * 4*ROWS
    float* cb = ws + 5 * 4 * ROWS;                // 5 * 8*ROWS
    float* ab = ws + 5 * 4 * ROWS + 5 * 8 * ROWS; // 4 * ROWS
#define HRB(t) (rb + (t) * 4 * ROWS)
#define HCB(t) (cb + (t) * (size_t)NCSL * ROWS)
#define HAB(t) (ab + ((t) - 1) * ROWS)

    float* outS = out;
    float* outC = out + 2 * ROWS;
    float4* outF = (float4*)(out + 4 * ROWS);

    // pre-zero ALL c slices + the 4 barrier counter sets (in-graph: reset on
    // every replay)
    hipMemsetAsync(cb, 0, 5 * (size_t)NCSL * ROWS * sizeof(float), stream);
    hipMemsetAsync(ab, 0, 4 * BARSTRIDE * sizeof(int), stream);

    dim3 gb(CSPLIT, NBY), bb(256, 1, 1);
    void* args[] = { (void*)&F4, (void*)&S2, (void*)&C2, (void*)&w,
                     (void*)&ws, (void*)&outF };
    hipError_t ce = hipLaunchCooperativeKernel((const void*)kfused, gb, bb,
                                               args, 0, stream);
    if (ce != hipSuccess) {
        // clear sticky error, run the proven multi-launch path
        (void)hipGetLastError();
        kbig<0><<<gb, bb, 0, stream>>>(F4, S2, C2, w, nullptr, nullptr, nullptr, nullptr,
                                       HRB(0), HCB(0), HCB(1), nullptr, nullptr);
        kbig<1><<<gb, bb, 0, stream>>>(F4, S2, C2, w, HRB(0), HCB(0), nullptr, nullptr,
                                       HRB(1), HCB(1), HCB(2), HAB(1), nullptr);
        kbig<2><<<gb, bb, 0, stream>>>(F4, S2, C2, w, HRB(1), HCB(1), HAB(1), nullptr,
                                       HRB(2), HCB(2), HCB(3), HAB(2), nullptr);
        kbig<3><<<gb, bb, 0, stream>>>(F4, S2, C2, w, HRB(2), HCB(2), HAB(2), HAB(1),
                                       HRB(3), HCB(3), HCB(4), HAB(3), nullptr);
        kbig<4><<<gb, bb, 0, stream>>>(F4, S2, C2, w, HRB(3), HCB(3), HAB(3), HAB(2),
                                       HRB(4), HCB(4), nullptr, HAB(4), outF);
    }
    kfin<<<dim3(ROWS/256), bb, 0, stream>>>(S2, C2, w, HRB(4), HCB(4), HAB(4), HAB(3),
                                            (float2*)outS, (float2*)outC);
}